// Round 2
// baseline (2131.838 us; speedup 1.0000x reference)
//
#include <hip/hip_runtime.h>
#include <hip/hip_bf16.h>

// Problem geometry (fixed by the reference)
#define SEQ   256
#define BATCH 256
#define HID   1024
#define KDIM  1024
#define MTOT  (SEQ*BATCH)   // 65536 rows for the batched GEMMs
#define BH    (BATCH*HID)   // 262144

typedef __bf16 bf16x8 __attribute__((ext_vector_type(8)));
typedef float  f32x4  __attribute__((ext_vector_type(4)));

__device__ __forceinline__ ushort f2b(float f){
    __hip_bfloat16 h = __float2bfloat16(f);
    return __builtin_bit_cast(ushort, h);
}
__device__ __forceinline__ float b2f(ushort u){
    __hip_bfloat16 h = __builtin_bit_cast(__hip_bfloat16, u);
    return __bfloat162float(h);
}

// ---------- f32 -> bf16 conversion of X (vectorized: float4 in, ushort4 out) ----------
__global__ void cvt_x(const float4* __restrict__ x, ushort4* __restrict__ o){
    int i = blockIdx.x * blockDim.x + threadIdx.x;
    float4 v = x[i];
    ushort4 r;
    r.x = f2b(v.x); r.y = f2b(v.y); r.z = f2b(v.z); r.w = f2b(v.w);
    o[i] = r;
}

// ---------- weight transpose + bf16: W[1025][1024] f32 -> Wt[n][k] bf16 ----------
__global__ void cvt_w(const float* __restrict__ W, ushort* __restrict__ Wt){
    __shared__ float tile[32][33];            // +1 pad: no LDS bank conflicts
    int tx = threadIdx.x & 31, ty = threadIdx.x >> 5;   // 32x8
    int kb = blockIdx.x * 32, nb = blockIdx.y * 32;
    #pragma unroll
    for (int j = 0; j < 32; j += 8)
        tile[ty + j][tx] = W[(size_t)(kb + ty + j) * HID + nb + tx];
    __syncthreads();
    #pragma unroll
    for (int j = 0; j < 32; j += 8)
        Wt[(size_t)(nb + ty + j) * KDIM + kb + tx] = f2b(tile[tx][ty + j]);
}

// ---------- extract time row W[1024][:] as f32 ----------
__global__ void cvt_time(const float* __restrict__ W, float* __restrict__ wt){
    int i = blockIdx.x * blockDim.x + threadIdx.x;
    wt[i] = W[(size_t)KDIM * HID + i];
}

// ---------- bf16 MFMA GEMM + sigmoid epilogue -> bf16 gate buffer ----------
// C[row, col] = sigmoid( sum_k A[row,k]*Wt[col,k] + (row>>8)/256 * wtime[col] + bias[col] )
// m97 structure: 128x128 tile, BK=32, 4 waves (2x2) of 64x64, global_load_lds width 16.
__global__ __launch_bounds__(256) void gemm_gate(
        const ushort* __restrict__ A, const ushort* __restrict__ Wt,
        const float* __restrict__ wtime, const float* __restrict__ bias,
        ushort* __restrict__ G)
{
    __shared__ ushort As[128 * 32];  // [row][k] row-major, 64B rows
    __shared__ ushort Bs[128 * 32];  // [n][k]

    const int tid  = threadIdx.x;
    const int lane = tid & 63;
    const int wid  = tid >> 6;           // wave 0..3
    const int wrow = wid >> 1;           // 2x2 wave grid over the 128x128 tile
    const int wcol = wid & 1;
    const size_t m0 = (size_t)blockIdx.x * 128;
    const int    n0 = blockIdx.y * 128;

    f32x4 acc[4][4];
    #pragma unroll
    for (int i = 0; i < 4; ++i)
        #pragma unroll
        for (int j = 0; j < 4; ++j)
            acc[i][j] = (f32x4){0.f, 0.f, 0.f, 0.f};

    const int lr = lane & 15;            // fragment row/col within 16
    const int lg = lane >> 4;            // k-group 0..3
    const int srow   = lane >> 2;        // staging: 4 lanes per 64B row
    const int schunk = lane & 3;         // 16B chunk within row

    for (int k0 = 0; k0 < KDIM; k0 += 32){
        // each wave stages 32 rows of A and 32 rows of B (2 calls of 16 rows each)
        #pragma unroll
        for (int c = 0; c < 2; ++c){
            const int r = wid * 32 + c * 16;  // wave-uniform row base
            const ushort* gA = A  + (m0 + r + srow) * KDIM + k0 + schunk * 8;
            __builtin_amdgcn_global_load_lds(
                (const __attribute__((address_space(1))) void*)gA,
                (__attribute__((address_space(3))) void*)(As + r * 32), 16, 0, 0);
            const ushort* gB = Wt + ((size_t)(n0 + r + srow)) * KDIM + k0 + schunk * 8;
            __builtin_amdgcn_global_load_lds(
                (const __attribute__((address_space(1))) void*)gB,
                (__attribute__((address_space(3))) void*)(Bs + r * 32), 16, 0, 0);
        }
        __syncthreads();   // compiler drains vmcnt before s_barrier

        bf16x8 a[4], b[4];
        #pragma unroll
        for (int m = 0; m < 4; ++m)
            a[m] = *(const bf16x8*)&As[(wrow * 64 + m * 16 + lr) * 32 + lg * 8];
        #pragma unroll
        for (int n = 0; n < 4; ++n)
            b[n] = *(const bf16x8*)&Bs[(wcol * 64 + n * 16 + lr) * 32 + lg * 8];

        #pragma unroll
        for (int m = 0; m < 4; ++m)
            #pragma unroll
            for (int n = 0; n < 4; ++n)
                acc[m][n] = __builtin_amdgcn_mfma_f32_16x16x32_bf16(a[m], b[n], acc[m][n], 0, 0, 0);
        __syncthreads();
    }

    // epilogue: add time term + bias, sigmoid, store bf16
    #pragma unroll
    for (int m = 0; m < 4; ++m){
        #pragma unroll
        for (int n = 0; n < 4; ++n){
            const int gcol = n0 + wcol * 64 + n * 16 + lr;
            const float wt_c = wtime[gcol];
            const float bi_c = bias[gcol];
            #pragma unroll
            for (int r = 0; r < 4; ++r){
                const size_t grow = m0 + wrow * 64 + m * 16 + lg * 4 + r;
                const int t = (int)(grow >> 8);          // row = t*BATCH + b
                const float pre = acc[m][n][r] + (float)t * (1.0f / 256.0f) * wt_c + bi_c;
                const float s = 1.0f / (1.0f + __expf(-pre));
                G[grow * HID + gcol] = f2b(s);
            }
        }
    }
}

// ---------- layer-0 scan: c = f*c + i*g; store c0_t (bf16, feeds layer 1) + final f32 ----------
__global__ void scan0(const ushort* __restrict__ gi, const ushort* __restrict__ gf,
                      const ushort* __restrict__ gg, ushort* __restrict__ c0b,
                      float* __restrict__ out){
    int idx = blockIdx.x * blockDim.x + threadIdx.x;  // (b,h) 0..BH-1
    float c = 0.f;
    for (int t = 0; t < SEQ; ++t){
        size_t off = (size_t)t * BH + idx;
        float i = b2f(gi[off]);
        float f = b2f(gf[off]);
        float g = b2f(gg[off]);
        c = f * c + i * g;
        c0b[off] = f2b(c);
    }
    out[idx] = c;
}

// ---------- layer-1 scan: only final state needed ----------
__global__ void scan1(const ushort* __restrict__ gi, const ushort* __restrict__ gf,
                      const ushort* __restrict__ gg, float* __restrict__ out){
    int idx = blockIdx.x * blockDim.x + threadIdx.x;
    float c = 0.f;
    for (int t = 0; t < SEQ; ++t){
        size_t off = (size_t)t * BH + idx;
        float i = b2f(gi[off]);
        float f = b2f(gf[off]);
        float g = b2f(gg[off]);
        c = f * c + i * g;
    }
    out[BH + idx] = c;
}

extern "C" void kernel_launch(void* const* d_in, const int* in_sizes, int n_in,
                              void* d_out, int out_size, void* d_ws, size_t ws_size,
                              hipStream_t stream){
    const float* x  = (const float*)d_in[0];
    const float* W0[3] = {(const float*)d_in[1], (const float*)d_in[2], (const float*)d_in[3]};
    const float* b0[3] = {(const float*)d_in[4], (const float*)d_in[5], (const float*)d_in[6]};
    const float* W1[3] = {(const float*)d_in[7], (const float*)d_in[8], (const float*)d_in[9]};
    const float* b1[3] = {(const float*)d_in[10], (const float*)d_in[11], (const float*)d_in[12]};
    float* out = (float*)d_out;

    // workspace layout (total ~527 MiB)
    char* ws = (char*)d_ws;
    ushort* xb  = (ushort*)ws;                                  // 128 MiB: X bf16, reused as c0 bf16
    ushort* gi  = (ushort*)(ws + (size_t)134217728);            // 128 MiB
    ushort* gf  = (ushort*)(ws + (size_t)268435456);            // 128 MiB
    ushort* gg  = (ushort*)(ws + (size_t)402653184);            // 128 MiB
    ushort* Wt  = (ushort*)(ws + (size_t)536870912);            // 6 x 2 MiB (bf16, [n][k])
    float*  wtm = (float*)(ws + (size_t)536870912 + (size_t)6 * 2097152); // 6 x 4 KiB
    ushort* gates[3] = {gi, gf, gg};

    // X f32 -> bf16 (67.1M elems, 4/thread)
    cvt_x<<<MTOT * KDIM / 4 / 256, 256, 0, stream>>>((const float4*)x, (ushort4*)xb);

    // weights: transpose+bf16, extract time rows
    dim3 tgrid(32, 32);
    for (int j = 0; j < 3; ++j){
        cvt_w  <<<tgrid, 256, 0, stream>>>(W0[j], Wt + (size_t)j * 1048576);
        cvt_time<<<4, 256, 0, stream>>>(W0[j], wtm + j * 1024);
        cvt_w  <<<tgrid, 256, 0, stream>>>(W1[j], Wt + (size_t)(3 + j) * 1048576);
        cvt_time<<<4, 256, 0, stream>>>(W1[j], wtm + (3 + j) * 1024);
    }

    dim3 ggrid(MTOT / 128, HID / 128);  // 512 x 8

    // layer 0: 3 batched gate GEMMs over X, then elementwise scan -> c0 (into xb)
    for (int j = 0; j < 3; ++j)
        gemm_gate<<<ggrid, 256, 0, stream>>>(xb, Wt + (size_t)j * 1048576,
                                             wtm + j * 1024, b0[j], gates[j]);
    scan0<<<BH / 256, 256, 0, stream>>>(gi, gf, gg, xb, out);

    // layer 1: 3 batched gate GEMMs over c0, then scan -> final c1
    for (int j = 0; j < 3; ++j)
        gemm_gate<<<ggrid, 256, 0, stream>>>(xb, Wt + (size_t)(3 + j) * 1048576,
                                             wtm + (3 + j) * 1024, b1[j], gates[j]);
    scan1<<<BH / 256, 256, 0, stream>>>(gi, gf, gg, out);
}

// Round 4
// 1766.744 us; speedup vs baseline: 1.2066x; 1.2066x over previous
//
#include <hip/hip_runtime.h>
#include <hip/hip_bf16.h>

// Problem geometry (fixed by the reference)
#define SEQ   256
#define BATCH 256
#define HID   1024
#define KDIM  1024
#define MTOT  (SEQ*BATCH)   // 65536 rows for the batched GEMMs
#define BH    (BATCH*HID)   // 262144
#define NF    3072          // fused gate columns: [i | f | g]

typedef __bf16 bf16x8 __attribute__((ext_vector_type(8)));
typedef float  f32x4  __attribute__((ext_vector_type(4)));

__device__ __forceinline__ ushort f2b(float f){
    __hip_bfloat16 h = __float2bfloat16(f);
    return __builtin_bit_cast(ushort, h);
}
__device__ __forceinline__ float b2f(ushort u){
    __hip_bfloat16 h = __builtin_bit_cast(__hip_bfloat16, u);
    return __bfloat162float(h);
}

// ---------- f32 -> bf16 conversion of X (float4 in, ushort4 out) ----------
__global__ void cvt_x(const float4* __restrict__ x, ushort4* __restrict__ o){
    int i = blockIdx.x * blockDim.x + threadIdx.x;
    float4 v = x[i];
    ushort4 r;
    r.x = f2b(v.x); r.y = f2b(v.y); r.z = f2b(v.z); r.w = f2b(v.w);
    o[i] = r;
}

// ---------- weight transpose + bf16: W[1025][1024] f32 -> Wt[n][k] bf16 ----------
__global__ void cvt_w(const float* __restrict__ W, ushort* __restrict__ Wt){
    __shared__ float tile[32][33];            // +1 pad: no LDS bank conflicts
    int tx = threadIdx.x & 31, ty = threadIdx.x >> 5;   // 32x8
    int kb = blockIdx.x * 32, nb = blockIdx.y * 32;
    #pragma unroll
    for (int j = 0; j < 32; j += 8)
        tile[ty + j][tx] = W[(size_t)(kb + ty + j) * HID + nb + tx];
    __syncthreads();
    #pragma unroll
    for (int j = 0; j < 32; j += 8)
        Wt[(size_t)(nb + ty + j) * KDIM + kb + tx] = f2b(tile[tx][ty + j]);
}

// ---------- per-gate column data: time row (W[1024][:]) + bias, into concat buffers ----------
__global__ void prep_cols(const float* __restrict__ W, const float* __restrict__ b,
                          float* __restrict__ wtv, float* __restrict__ bcat){
    int i = blockIdx.x * blockDim.x + threadIdx.x;   // 0..1023
    wtv[i]  = W[(size_t)KDIM * HID + i];
    bcat[i] = b[i];
}

// ---------- fused 3-gate bf16 MFMA GEMM + sigmoid epilogue ----------
// G[row, col] = sigmoid( sum_k A[row,k]*Wt[col,k] + (row>>8)/256*wtv[col] + bcat[col] )
// 128x128 tile, BK=32, 4 waves (2x2), double-buffered LDS, global_load_lds w=16,
// both-sides K-chunk XOR swizzle (2-way bank aliasing = free),
// XCD-chunked block mapping: each XCD owns 64 M-panels; 12 N-blocks innermost
// so an A-panel is fetched once into the XCD's L2 and reused; B-half (3MB) stays hot.
__global__ __launch_bounds__(256) void gemm_gate3(
        const ushort* __restrict__ A, const ushort* __restrict__ Wt,
        const float* __restrict__ wtv, const float* __restrict__ bcat,
        ushort* __restrict__ G)
{
    __shared__ ushort As[2][128 * 32];
    __shared__ ushort Bs[2][128 * 32];

    const int tid  = threadIdx.x;
    const int lane = tid & 63;
    const int wid  = tid >> 6;
    const int wrow = wid >> 1;
    const int wcol = wid & 1;

    // swizzled block mapping: grid = 12288 linear = 8 xcd * (2 nhalf * 64 mp * 12 nb)
    const int bid  = blockIdx.x;
    const int xcd  = bid & 7;
    const int slot = bid >> 3;            // 0..1535 (per-XCD sequence)
    const int nh   = slot / 768;          // N-half 0/1
    const int rem  = slot - nh * 768;
    const int mp   = rem / 12;            // 0..63
    const int nb   = rem - mp * 12 + nh * 12;  // 0..23
    const size_t m0 = ((size_t)(xcd * 64 + mp)) * 128;
    const int    n0 = nb * 128;

    f32x4 acc[4][4];
    #pragma unroll
    for (int i = 0; i < 4; ++i)
        #pragma unroll
        for (int j = 0; j < 4; ++j)
            acc[i][j] = (f32x4){0.f, 0.f, 0.f, 0.f};

    const int lr = lane & 15;             // fragment row within 16
    const int lg = lane >> 4;             // k-group 0..3
    const int srow   = lane >> 2;         // staging row within 16-row block
    const int schunk = lane & 3;          // 16B slot within 64B row
    // both-sides swizzle: LDS slot s of row r holds global k-chunk s ^ ((r>>1)&3)
    const int sk   = (schunk ^ ((srow >> 1) & 3)) * 8;  // staging source k-offset (ushorts)
    const int axor = (lg ^ ((lr >> 1) & 3)) * 8;        // read-side slot offset (ushorts)

    int buf = 0;
    auto stage = [&](int bsel, int k0){
        #pragma unroll
        for (int c = 0; c < 2; ++c){
            const int r = wid * 32 + c * 16;  // wave-uniform row base
            const ushort* gA = A + (m0 + r + srow) * KDIM + k0 + sk;
            __builtin_amdgcn_global_load_lds(
                (const __attribute__((address_space(1))) void*)gA,
                (__attribute__((address_space(3))) void*)(&As[bsel][r * 32]), 16, 0, 0);
            const ushort* gB = Wt + (size_t)(n0 + r + srow) * KDIM + k0 + sk;
            __builtin_amdgcn_global_load_lds(
                (const __attribute__((address_space(1))) void*)gB,
                (__attribute__((address_space(3))) void*)(&Bs[bsel][r * 32]), 16, 0, 0);
        }
    };

    stage(0, 0);
    __syncthreads();   // compiler drains vmcnt before s_barrier

    for (int kt = 0; kt < 32; ++kt){
        if (kt != 31) stage(buf ^ 1, (kt + 1) * 32);   // prefetch next tile FIRST

        bf16x8 a[4], b[4];
        #pragma unroll
        for (int m = 0; m < 4; ++m)
            a[m] = *(const bf16x8*)&As[buf][(wrow * 64 + m * 16 + lr) * 32 + axor];
        #pragma unroll
        for (int n = 0; n < 4; ++n)
            b[n] = *(const bf16x8*)&Bs[buf][(wcol * 64 + n * 16 + lr) * 32 + axor];

        #pragma unroll
        for (int m = 0; m < 4; ++m)
            #pragma unroll
            for (int n = 0; n < 4; ++n)
                acc[m][n] = __builtin_amdgcn_mfma_f32_16x16x32_bf16(a[m], b[n], acc[m][n], 0, 0, 0);

        __syncthreads();   // drains prefetch vmcnt + lgkm; next tile ready
        buf ^= 1;
    }

    // epilogue: time term + bias, sigmoid, store bf16
    #pragma unroll
    for (int m = 0; m < 4; ++m){
        #pragma unroll
        for (int n = 0; n < 4; ++n){
            const int gcol = n0 + wcol * 64 + n * 16 + lr;
            const float wt_c = wtv[gcol];
            const float bi_c = bcat[gcol];
            #pragma unroll
            for (int r = 0; r < 4; ++r){
                const size_t grow = m0 + wrow * 64 + m * 16 + lg * 4 + r;
                const int t = (int)(grow >> 8);          // row = t*BATCH + b
                const float pre = acc[m][n][r] + (float)t * (1.0f / 256.0f) * wt_c + bi_c;
                const float s = 1.0f / (1.0f + __expf(-pre));
                G[grow * NF + gcol] = f2b(s);
            }
        }
    }
}

// ---------- layer-0 scan over G[row][3072]: c = f*c + i*g; c0 (bf16) + final f32 ----------
__global__ void scan0(const ushort* __restrict__ G, ushort* __restrict__ c0b,
                      float* __restrict__ out){
    int idx = blockIdx.x * blockDim.x + threadIdx.x;  // b*HID + h
    int b = idx >> 10, h = idx & 1023;
    float c = 0.f;
    for (int t = 0; t < SEQ; ++t){
        size_t base = (size_t)(t * BATCH + b) * NF + h;
        float i = b2f(G[base]);
        float f = b2f(G[base + 1024]);
        float g = b2f(G[base + 2048]);
        c = f * c + i * g;
        c0b[(size_t)(t * BATCH + b) * KDIM + h] = f2b(c);
    }
    out[idx] = c;
}

// ---------- layer-1 scan: only final state ----------
__global__ void scan1(const ushort* __restrict__ G, float* __restrict__ out){
    int idx = blockIdx.x * blockDim.x + threadIdx.x;
    int b = idx >> 10, h = idx & 1023;
    float c = 0.f;
    for (int t = 0; t < SEQ; ++t){
        size_t base = (size_t)(t * BATCH + b) * NF + h;
        float i = b2f(G[base]);
        float f = b2f(G[base + 1024]);
        float g = b2f(G[base + 2048]);
        c = f * c + i * g;
    }
    out[BH + idx] = c;
}

extern "C" void kernel_launch(void* const* d_in, const int* in_sizes, int n_in,
                              void* d_out, int out_size, void* d_ws, size_t ws_size,
                              hipStream_t stream){
    const float* x  = (const float*)d_in[0];
    const float* W0[3] = {(const float*)d_in[1], (const float*)d_in[2], (const float*)d_in[3]};
    const float* b0[3] = {(const float*)d_in[4], (const float*)d_in[5], (const float*)d_in[6]};
    const float* W1[3] = {(const float*)d_in[7], (const float*)d_in[8], (const float*)d_in[9]};
    const float* b1[3] = {(const float*)d_in[10], (const float*)d_in[11], (const float*)d_in[12]};
    float* out = (float*)d_out;

    // workspace layout (~550 MiB)
    char* ws = (char*)d_ws;
    ushort* xb  = (ushort*)ws;                               // 128 MiB: X bf16, then c0 bf16
    ushort* G   = (ushort*)(ws + (size_t)134217728);         // 402653184 B: fused gates [65536][3072]
    ushort* Wt0 = (ushort*)(ws + (size_t)536870912);         // 6 MiB: layer-0 [3072][1024] bf16
    ushort* Wt1 = (ushort*)(ws + (size_t)543162368);         // 6 MiB: layer-1
    float*  wtv0 = (float*)(ws + (size_t)549453824);         // 3072 f32 time-row
    float*  bc0  = (float*)(ws + (size_t)549453824 + 12288); // 3072 f32 bias
    float*  wtv1 = (float*)(ws + (size_t)549453824 + 24576);
    float*  bc1  = (float*)(ws + (size_t)549453824 + 36864);

    // X f32 -> bf16
    cvt_x<<<MTOT * KDIM / 4 / 256, 256, 0, stream>>>((const float4*)x, (ushort4*)xb);

    // weights: transpose+bf16 into concat [3072][1024]; time rows + biases into concat cols
    dim3 tgrid(32, 32);
    for (int j = 0; j < 3; ++j){
        cvt_w<<<tgrid, 256, 0, stream>>>(W0[j], Wt0 + (size_t)j * 1048576);
        cvt_w<<<tgrid, 256, 0, stream>>>(W1[j], Wt1 + (size_t)j * 1048576);
        prep_cols<<<4, 256, 0, stream>>>(W0[j], b0[j], wtv0 + j * 1024, bc0 + j * 1024);
        prep_cols<<<4, 256, 0, stream>>>(W1[j], b1[j], wtv1 + j * 1024, bc1 + j * 1024);
    }

    // layer 0: fused gate GEMM over X, then scan -> c0 (into xb) + out[0]
    gemm_gate3<<<12288, 256, 0, stream>>>(xb, Wt0, wtv0, bc0, G);
    scan0<<<BH / 256, 256, 0, stream>>>(G, xb, out);

    // layer 1: fused gate GEMM over c0, then scan -> out[1]
    gemm_gate3<<<12288, 256, 0, stream>>>(xb, Wt1, wtv1, bc1, G);
    scan1<<<BH / 256, 256, 0, stream>>>(G, out);
}